// Round 2
// baseline (1240.217 us; speedup 1.0000x reference)
//
#include <hip/hip_runtime.h>

typedef unsigned short u16;
typedef __attribute__((ext_vector_type(8))) short short8;
typedef __attribute__((ext_vector_type(4))) float floatx4;

#define B_ 16
#define T_ 1024
#define D_ 1024
#define H_ 8
#define HD_ 128
#define NQKV 3072   // Q|K|V concatenated along N

__device__ __forceinline__ u16 f2bf(float f) {
    unsigned u = __float_as_uint(f);
    unsigned r = (u + 0x7fffu + ((u >> 16) & 1u)) >> 16;
    return (u16)r;
}
__device__ __forceinline__ float bf2f(u16 h) {
    return __uint_as_float(((unsigned)h) << 16);
}

// ---------------- cast x (f32 -> bf16), 4 elems/thread ----------------
__global__ void cast_x_kernel(const float* __restrict__ x, u16* __restrict__ xb, int n4) {
    int i = blockIdx.x * blockDim.x + threadIdx.x;
    if (i < n4) {
        float4 v = ((const float4*)x)[i];
        uint2 o;
        o.x = (unsigned)f2bf(v.x) | ((unsigned)f2bf(v.y) << 16);
        o.y = (unsigned)f2bf(v.z) | ((unsigned)f2bf(v.w) << 16);
        ((uint2*)xb)[i] = o;
    }
}

// ------- cast + transpose W: Wt[n][k] = W[k][n], n in [0,3072) -------
__global__ void cast_w_kernel(const float* __restrict__ Wq, const float* __restrict__ Wk,
                              const float* __restrict__ Wv, u16* __restrict__ Wt) {
    __shared__ float tile[32][33];
    const float* W = (blockIdx.z == 0) ? Wq : (blockIdx.z == 1) ? Wk : Wv;
    int k0 = blockIdx.x * 32, c0 = blockIdx.y * 32;
    int tx = threadIdx.x, ty = threadIdx.y;
    #pragma unroll
    for (int i = ty; i < 32; i += 8)
        tile[i][tx] = W[(size_t)(k0 + i) * D_ + c0 + tx];
    __syncthreads();
    #pragma unroll
    for (int i = ty; i < 32; i += 8)
        Wt[(size_t)(blockIdx.z * D_ + c0 + i) * D_ + k0 + tx] = f2bf(tile[tx][i]);
}

// ---------------- GEMM: C[16384][3072] = xb[16384][1024] * Wt^T ----------------
// Wt is [3072][1024] (n-major, k contiguous). C = bf16.
__global__ __launch_bounds__(256)
void gemm_kernel(const u16* __restrict__ A, const u16* __restrict__ Bt, u16* __restrict__ C) {
    __shared__ __align__(16) u16 As[128 * 32];
    __shared__ __align__(16) u16 Bs[128 * 32];
    const int K = D_;
    const int N = NQKV;
    int m0 = blockIdx.x * 128, n0 = blockIdx.y * 128;
    int t = threadIdx.x;
    int w = t >> 6, lane = t & 63, lr = lane & 15, lk = lane >> 4;
    int wm = (w >> 1) * 64, wn = (w & 1) * 64;

    // staging map: byte offsets t*16 and 4096+t*16 in an 8192B tile ([128][32] bf16)
    int off0 = t * 16, off1 = 4096 + t * 16;
    int row0 = off0 >> 6, kc0 = (off0 & 63) >> 1;
    int row1 = off1 >> 6, kc1 = (off1 & 63) >> 1;

    floatx4 zero = {0.f, 0.f, 0.f, 0.f};
    floatx4 acc[4][4];
    #pragma unroll
    for (int i = 0; i < 4; i++)
        #pragma unroll
        for (int j = 0; j < 4; j++) acc[i][j] = zero;

    for (int k0 = 0; k0 < K; k0 += 32) {
        *(uint4*)&As[off0 >> 1] = *(const uint4*)&A[(size_t)(m0 + row0) * K + k0 + kc0];
        *(uint4*)&As[off1 >> 1] = *(const uint4*)&A[(size_t)(m0 + row1) * K + k0 + kc1];
        *(uint4*)&Bs[off0 >> 1] = *(const uint4*)&Bt[(size_t)(n0 + row0) * K + k0 + kc0];
        *(uint4*)&Bs[off1 >> 1] = *(const uint4*)&Bt[(size_t)(n0 + row1) * K + k0 + kc1];
        __syncthreads();
        short8 af[4], bf[4];
        #pragma unroll
        for (int i = 0; i < 4; i++)
            af[i] = *(const short8*)&As[(wm + i * 16 + lr) * 32 + lk * 8];
        #pragma unroll
        for (int i = 0; i < 4; i++)
            bf[i] = *(const short8*)&Bs[(wn + i * 16 + lr) * 32 + lk * 8];
        #pragma unroll
        for (int i = 0; i < 4; i++)
            #pragma unroll
            for (int j = 0; j < 4; j++)
                acc[i][j] = __builtin_amdgcn_mfma_f32_16x16x32_bf16(af[i], bf[j], acc[i][j], 0, 0, 0);
        __syncthreads();
    }
    // epilogue: C/D layout col=lane&15, row=(lane>>4)*4+reg
    #pragma unroll
    for (int i = 0; i < 4; i++)
        #pragma unroll
        for (int j = 0; j < 4; j++)
            #pragma unroll
            for (int r = 0; r < 4; r++) {
                int row = m0 + wm + i * 16 + lk * 4 + r;
                int col = n0 + wn + j * 16 + lr;
                C[(size_t)row * N + col] = f2bf(acc[i][j][r]);
            }
}

// ---------------- attention: logits + causal softmax, write attn f32 ----------------
// qkv: [B*T][3072] bf16 (Q cols 0..1023, K 1024..2047, V 2048..3071)
// attn: [B][H][T][T] f32
__global__ __launch_bounds__(256)
void attn_kernel(const u16* __restrict__ qkv, float* __restrict__ attn) {
    int w = threadIdx.x >> 6, lane = threadIdx.x & 63, lr = lane & 15, lk = lane >> 4;
    int qt = blockIdx.x * 4 + w;          // 0..63
    int h = blockIdx.y, b = blockIdx.z;
    int q0 = qt * 16;
    const float scale = 0.08838834764831845f;  // 1/sqrt(128)

    short8 aq[4];
    size_t qbase = ((size_t)(b * T_ + q0 + lr)) * NQKV + h * HD_;
    #pragma unroll
    for (int s = 0; s < 4; s++) aq[s] = *(const short8*)&qkv[qbase + s * 32 + lk * 8];

    float m[4], l[4];
    #pragma unroll
    for (int j = 0; j < 4; j++) { m[j] = -1e30f; l[j] = 0.f; }

    // pass 1: online max/sum
    for (int kt = 0; kt <= qt; ++kt) {
        floatx4 acc = {0.f, 0.f, 0.f, 0.f};
        size_t kbase = ((size_t)(b * T_ + kt * 16 + lr)) * NQKV + D_ + h * HD_;
        #pragma unroll
        for (int s = 0; s < 4; s++) {
            short8 bk = *(const short8*)&qkv[kbase + s * 32 + lk * 8];
            acc = __builtin_amdgcn_mfma_f32_16x16x32_bf16(aq[s], bk, acc, 0, 0, 0);
        }
        #pragma unroll
        for (int j = 0; j < 4; j++) {
            float sv = acc[j] * scale;
            if (kt == qt && (kt * 16 + lr) > (q0 + lk * 4 + j)) sv = -1e30f;
            float tm = sv;
            tm = fmaxf(tm, __shfl_xor(tm, 1));
            tm = fmaxf(tm, __shfl_xor(tm, 2));
            tm = fmaxf(tm, __shfl_xor(tm, 4));
            tm = fmaxf(tm, __shfl_xor(tm, 8));
            float mn = fmaxf(m[j], tm);
            float ex = __expf(sv - mn);
            float es = ex;
            es += __shfl_xor(es, 1);
            es += __shfl_xor(es, 2);
            es += __shfl_xor(es, 4);
            es += __shfl_xor(es, 8);
            l[j] = l[j] * __expf(m[j] - mn) + es;
            m[j] = mn;
        }
    }
    float rinv[4];
    #pragma unroll
    for (int j = 0; j < 4; j++) rinv[j] = 1.f / l[j];

    // pass 2: recompute + write normalized probs (zeros above diagonal)
    size_t obase = ((size_t)(b * H_ + h)) * T_ * T_;
    for (int kt = 0; kt < T_ / 16; ++kt) {
        float p[4] = {0.f, 0.f, 0.f, 0.f};
        if (kt <= qt) {
            floatx4 acc = {0.f, 0.f, 0.f, 0.f};
            size_t kbase = ((size_t)(b * T_ + kt * 16 + lr)) * NQKV + D_ + h * HD_;
            #pragma unroll
            for (int s = 0; s < 4; s++) {
                short8 bk = *(const short8*)&qkv[kbase + s * 32 + lk * 8];
                acc = __builtin_amdgcn_mfma_f32_16x16x32_bf16(aq[s], bk, acc, 0, 0, 0);
            }
            #pragma unroll
            for (int j = 0; j < 4; j++) {
                float sv = acc[j] * scale;
                if (kt == qt && (kt * 16 + lr) > (q0 + lk * 4 + j)) sv = -1e30f;
                p[j] = __expf(sv - m[j]) * rinv[j];
            }
        }
        #pragma unroll
        for (int j = 0; j < 4; j++) {
            int q = q0 + lk * 4 + j;
            attn[obase + (size_t)q * T_ + kt * 16 + lr] = p[j];
        }
    }
}

// ---------------- context: out[b][h*128+hd] = sum_k attn[b,h,T-1,k] * V[b,k,h,hd] ----------------
__global__ __launch_bounds__(128)
void context_kernel(const float* __restrict__ attn, const u16* __restrict__ qkv,
                    float* __restrict__ out) {
    int b = blockIdx.x, h = blockIdx.y, tid = threadIdx.x;  // tid = hd
    __shared__ float p[T_];
    const float* prow = attn + (((size_t)(b * H_ + h)) * T_ + (T_ - 1)) * T_;
    for (int i = tid; i < T_; i += 128) p[i] = prow[i];
    __syncthreads();
    size_t vbase = (size_t)b * T_ * NQKV + 2 * D_ + h * HD_ + tid;
    float a0 = 0.f, a1 = 0.f, a2 = 0.f, a3 = 0.f;
    for (int k = 0; k < T_; k += 4) {
        a0 += p[k + 0] * bf2f(qkv[vbase + (size_t)(k + 0) * NQKV]);
        a1 += p[k + 1] * bf2f(qkv[vbase + (size_t)(k + 1) * NQKV]);
        a2 += p[k + 2] * bf2f(qkv[vbase + (size_t)(k + 2) * NQKV]);
        a3 += p[k + 3] * bf2f(qkv[vbase + (size_t)(k + 3) * NQKV]);
    }
    out[(size_t)b * D_ + h * HD_ + tid] = (a0 + a1) + (a2 + a3);
}

extern "C" void kernel_launch(void* const* d_in, const int* in_sizes, int n_in,
                              void* d_out, int out_size, void* d_ws, size_t ws_size,
                              hipStream_t stream) {
    const float* x  = (const float*)d_in[0];
    const float* Wq = (const float*)d_in[1];
    const float* Wk = (const float*)d_in[2];
    const float* Wv = (const float*)d_in[3];
    float* out = (float*)d_out;

    u16* xb  = (u16*)d_ws;                       // [16384][1024] bf16, 32 MB
    u16* Wt  = xb + (size_t)B_ * T_ * D_;        // [3072][1024] bf16, 6 MB
    u16* qkv = Wt + (size_t)NQKV * D_;           // [16384][3072] bf16, 96 MB

    // 1. cast x to bf16
    int n4 = B_ * T_ * D_ / 4;
    cast_x_kernel<<<n4 / 256, 256, 0, stream>>>(x, xb, n4);
    // 2. cast+transpose weights
    cast_w_kernel<<<dim3(32, 32, 3), dim3(32, 8), 0, stream>>>(Wq, Wk, Wv, Wt);
    // 3. fused QKV projection GEMM
    gemm_kernel<<<dim3(128, 24), 256, 0, stream>>>(xb, Wt, qkv);
    // 4. attention scores + causal softmax (writes attn weights output)
    attn_kernel<<<dim3(16, 8, 16), 256, 0, stream>>>(qkv, out + B_ * D_);
    // 5. context = last-row PV
    context_kernel<<<dim3(B_, H_), 128, 0, stream>>>(out + B_ * D_, qkv, out);
}

// Round 5
// 942.416 us; speedup vs baseline: 1.3160x; 1.3160x over previous
//
#include <hip/hip_runtime.h>

typedef unsigned short u16;
typedef __attribute__((ext_vector_type(8))) short short8;
typedef __attribute__((ext_vector_type(4))) float floatx4;

#define B_ 16
#define T_ 1024
#define D_ 1024
#define H_ 8
#define HD_ 128
#define NQKV 3072

#define GLD16(g, l)                                                                   \
    __builtin_amdgcn_global_load_lds((const __attribute__((address_space(1))) unsigned*)(g), \
                                     (__attribute__((address_space(3))) unsigned*)(l), 16, 0, 0)

__device__ __forceinline__ u16 f2bf(float f) {
    unsigned u = __float_as_uint(f);
    unsigned r = (u + 0x7fffu + ((u >> 16) & 1u)) >> 16;
    return (u16)r;
}
__device__ __forceinline__ float bf2f(u16 h) {
    return __uint_as_float(((unsigned)h) << 16);
}

// ---------------- cast x (f32 -> bf16) ----------------
__global__ void cast_x_kernel(const float* __restrict__ x, u16* __restrict__ xb, int n4) {
    int i = blockIdx.x * blockDim.x + threadIdx.x;
    if (i < n4) {
        float4 v = ((const float4*)x)[i];
        uint2 o;
        o.x = (unsigned)f2bf(v.x) | ((unsigned)f2bf(v.y) << 16);
        o.y = (unsigned)f2bf(v.z) | ((unsigned)f2bf(v.w) << 16);
        ((uint2*)xb)[i] = o;
    }
}

// ------- cast + transpose W: Wt[n][k] = W[k][n] -------
__global__ void cast_w_kernel(const float* __restrict__ Wq, const float* __restrict__ Wk,
                              const float* __restrict__ Wv, u16* __restrict__ Wt) {
    __shared__ float tile[32][33];
    const float* W = (blockIdx.z == 0) ? Wq : (blockIdx.z == 1) ? Wk : Wv;
    int k0 = blockIdx.x * 32, c0 = blockIdx.y * 32;
    int tx = threadIdx.x, ty = threadIdx.y;
    #pragma unroll
    for (int i = ty; i < 32; i += 8)
        tile[i][tx] = W[(size_t)(k0 + i) * D_ + c0 + tx];
    __syncthreads();
    #pragma unroll
    for (int i = ty; i < 32; i += 8)
        Wt[(size_t)(blockIdx.z * D_ + c0 + i) * D_ + k0 + tx] = f2bf(tile[tx][i]);
}

// ---------------- GEMM: C[16384][3072] = xb * Wt^T, global_load_lds staging ----------------
__global__ __launch_bounds__(256)
void gemm_kernel(const u16* __restrict__ A, const u16* __restrict__ Bt, u16* __restrict__ C) {
    __shared__ __align__(16) u16 As[128 * 32];
    __shared__ __align__(16) u16 Bs[128 * 32];
    const int K = D_, N = NQKV;
    int bid = blockIdx.x;
    int idx = (bid & 7) * 384 + (bid >> 3);
    int m0 = (idx & 127) * 128, n0 = (idx >> 7) * 128;
    int t = threadIdx.x;
    int w = t >> 6, lane = t & 63, lr = lane & 15, lk = lane >> 4;
    int wm = (w >> 1) * 64, wn = (w & 1) * 64;

    int row0 = (w << 4) + (lane >> 2), kc0 = (lane & 3) << 3;
    const u16* gA0 = &A[(size_t)(m0 + row0) * K + kc0];
    const u16* gA1 = gA0 + (size_t)64 * K;
    const u16* gB0 = &Bt[(size_t)(n0 + row0) * K + kc0];
    const u16* gB1 = gB0 + (size_t)64 * K;
    u16* lA0 = &As[w * 512];
    u16* lB0 = &Bs[w * 512];

    floatx4 zero = {0.f, 0.f, 0.f, 0.f};
    floatx4 acc[4][4];
    #pragma unroll
    for (int i = 0; i < 4; i++)
        #pragma unroll
        for (int j = 0; j < 4; j++) acc[i][j] = zero;

    for (int k0 = 0; k0 < K; k0 += 32) {
        GLD16(gA0 + k0, lA0);
        GLD16(gA1 + k0, lA0 + 2048);
        GLD16(gB0 + k0, lB0);
        GLD16(gB1 + k0, lB0 + 2048);
        __syncthreads();
        short8 af[4], bf[4];
        #pragma unroll
        for (int i = 0; i < 4; i++)
            af[i] = *(const short8*)&As[(wm + i * 16 + lr) * 32 + lk * 8];
        #pragma unroll
        for (int i = 0; i < 4; i++)
            bf[i] = *(const short8*)&Bs[(wn + i * 16 + lr) * 32 + lk * 8];
        #pragma unroll
        for (int i = 0; i < 4; i++)
            #pragma unroll
            for (int j = 0; j < 4; j++)
                acc[i][j] = __builtin_amdgcn_mfma_f32_16x16x32_bf16(af[i], bf[j], acc[i][j], 0, 0, 0);
        __syncthreads();
    }
    #pragma unroll
    for (int i = 0; i < 4; i++)
        #pragma unroll
        for (int j = 0; j < 4; j++)
            #pragma unroll
            for (int r = 0; r < 4; r++) {
                int row = m0 + wm + i * 16 + lk * 4 + r;
                int col = n0 + wn + j * 16 + lr;
                C[(size_t)row * N + col] = f2bf(acc[i][j][r]);
            }
}

// ---------------- attention: balanced, reg->ds_write staged K, per-lane online softmax ----------------
// grid: 1024 blocks. bid%8 = XCD; blocks sharing (b,h) land on the same XCD.
__global__ __launch_bounds__(256)
void attn_kernel(const u16* __restrict__ qkv, float* __restrict__ attn) {
    int bid = blockIdx.x;
    int xcd = bid & 7;
    int i = bid >> 3;
    int p = i & 7;
    int b = i >> 3;
    int h = (xcd - b) & 7;
    int t = threadIdx.x;
    int w = t >> 6, lane = t & 63, lr = lane & 15, lk = lane >> 4;
    int slot = p * 4 + w;
    int qtA = slot, qtB = 63 - slot;
    int kmax = 63 - 4 * p;
    const float sc2 = 0.08838834764831845f * 1.44269504088896340736f;  // scale * log2(e)

    __shared__ __align__(16) u16 Ks[2 * 16 * 128];  // 2 buffers x 4KB

    // Q fragments for both owned q-tiles
    short8 aqA[4], aqB[4];
    size_t qbA = ((size_t)(b * T_ + qtA * 16 + lr)) * NQKV + h * HD_;
    size_t qbB = ((size_t)(b * T_ + qtB * 16 + lr)) * NQKV + h * HD_;
    #pragma unroll
    for (int s = 0; s < 4; s++) {
        aqA[s] = *(const short8*)&qkv[qbA + s * 32 + lk * 8];
        aqB[s] = *(const short8*)&qkv[qbB + s * 32 + lk * 8];
    }

    // staging: thread t loads row srow=t>>4, chunk t&15 (LINEAR source);
    // writes LDS at swizzled chunk (t&15)^(srow&7). Read side applies same XOR.
    int srow = t >> 4;
    const u16* ksrc = qkv + ((size_t)(b * T_ + srow)) * NQKV + D_ + h * HD_ + (t & 15) * 8;
    int wofs = srow * 128 + (((t & 15) ^ (srow & 7)) << 3);  // u16 units within buffer

    float mA[4], lA[4], mB[4], lB[4];
    #pragma unroll
    for (int j = 0; j < 4; j++) { mA[j] = -1e30f; lA[j] = 0.f; mB[j] = -1e30f; lB[j] = 0.f; }

    short8 stg = *(const short8*)ksrc;  // kt=0
    *(short8*)&Ks[wofs] = stg;          // buffer 0

    // ---- sweep 1: online max/sum ----
    for (int kt = 0; kt <= kmax; ++kt) {
        int buf = (kt & 1) * 2048;
        if (kt < kmax) stg = *(const short8*)(ksrc + (size_t)(kt + 1) * 16 * NQKV);
        __syncthreads();  // publishes ds_write of buf; all reads of buf^2048 done
        if (kt <= qtA) {
            floatx4 acc = {0.f, 0.f, 0.f, 0.f};
            #pragma unroll
            for (int s = 0; s < 4; s++) {
                int ch = ((s << 2) + lk) ^ (lr & 7);
                short8 bk = *(const short8*)&Ks[buf + lr * 128 + ch * 8];
                acc = __builtin_amdgcn_mfma_f32_16x16x32_bf16(aqA[s], bk, acc, 0, 0, 0);
            }
            #pragma unroll
            for (int j = 0; j < 4; j++) {
                float s2 = acc[j] * sc2;
                if (kt == qtA && lr > lk * 4 + j) s2 = -1e30f;
                float nm = fmaxf(mA[j], s2);
                lA[j] = lA[j] * exp2f(mA[j] - nm) + exp2f(s2 - nm);
                mA[j] = nm;
            }
        }
        if (kt <= qtB) {
            floatx4 acc = {0.f, 0.f, 0.f, 0.f};
            #pragma unroll
            for (int s = 0; s < 4; s++) {
                int ch = ((s << 2) + lk) ^ (lr & 7);
                short8 bk = *(const short8*)&Ks[buf + lr * 128 + ch * 8];
                acc = __builtin_amdgcn_mfma_f32_16x16x32_bf16(aqB[s], bk, acc, 0, 0, 0);
            }
            #pragma unroll
            for (int j = 0; j < 4; j++) {
                float s2 = acc[j] * sc2;
                if (kt == qtB && lr > lk * 4 + j) s2 = -1e30f;
                float nm = fmaxf(mB[j], s2);
                lB[j] = lB[j] * exp2f(mB[j] - nm) + exp2f(s2 - nm);
                mB[j] = nm;
            }
        }
        if (kt < kmax) *(short8*)&Ks[(buf ^ 2048) + wofs] = stg;
    }

    // ---- merge (m,l) across the 16 lr lanes ----
    float rA[4], rB[4];
    #pragma unroll
    for (int j = 0; j < 4; j++) {
        float m_ = mA[j], l_ = lA[j];
        #pragma unroll
        for (int d = 1; d < 16; d <<= 1) {
            float om = __shfl_xor(m_, d), ol = __shfl_xor(l_, d);
            float nm = fmaxf(m_, om);
            l_ = l_ * exp2f(m_ - nm) + ol * exp2f(om - nm);
            m_ = nm;
        }
        mA[j] = m_; rA[j] = 1.f / l_;
        m_ = mB[j]; l_ = lB[j];
        #pragma unroll
        for (int d = 1; d < 16; d <<= 1) {
            float om = __shfl_xor(m_, d), ol = __shfl_xor(l_, d);
            float nm = fmaxf(m_, om);
            l_ = l_ * exp2f(m_ - nm) + ol * exp2f(om - nm);
            m_ = nm;
        }
        mB[j] = m_; rB[j] = 1.f / l_;
    }

    // ---- sweep 2: recompute + write ----
    size_t obase = ((size_t)(b * H_ + h)) * T_ * T_;
    size_t orowA = obase + (size_t)(qtA * 16 + lk * 4) * T_ + lr;
    size_t orowB = obase + (size_t)(qtB * 16 + lk * 4) * T_ + lr;
    stg = *(const short8*)ksrc;  // kt=0 again
    __syncthreads();             // all sweep-1 reads done before overwriting buffer 0
    *(short8*)&Ks[wofs] = stg;
    for (int kt = 0; kt <= kmax; ++kt) {
        int buf = (kt & 1) * 2048;
        if (kt < kmax) stg = *(const short8*)(ksrc + (size_t)(kt + 1) * 16 * NQKV);
        __syncthreads();
        if (kt <= qtA) {
            floatx4 acc = {0.f, 0.f, 0.f, 0.f};
            #pragma unroll
            for (int s = 0; s < 4; s++) {
                int ch = ((s << 2) + lk) ^ (lr & 7);
                short8 bk = *(const short8*)&Ks[buf + lr * 128 + ch * 8];
                acc = __builtin_amdgcn_mfma_f32_16x16x32_bf16(aqA[s], bk, acc, 0, 0, 0);
            }
            #pragma unroll
            for (int j = 0; j < 4; j++) {
                float s2 = acc[j] * sc2;
                if (kt == qtA && lr > lk * 4 + j) s2 = -1e30f;
                attn[orowA + (size_t)j * T_ + kt * 16] = exp2f(s2 - mA[j]) * rA[j];
            }
        } else {
            #pragma unroll
            for (int j = 0; j < 4; j++) attn[orowA + (size_t)j * T_ + kt * 16] = 0.f;
        }
        if (kt <= qtB) {
            floatx4 acc = {0.f, 0.f, 0.f, 0.f};
            #pragma unroll
            for (int s = 0; s < 4; s++) {
                int ch = ((s << 2) + lk) ^ (lr & 7);
                short8 bk = *(const short8*)&Ks[buf + lr * 128 + ch * 8];
                acc = __builtin_amdgcn_mfma_f32_16x16x32_bf16(aqB[s], bk, acc, 0, 0, 0);
            }
            #pragma unroll
            for (int j = 0; j < 4; j++) {
                float s2 = acc[j] * sc2;
                if (kt == qtB && lr > lk * 4 + j) s2 = -1e30f;
                attn[orowB + (size_t)j * T_ + kt * 16] = exp2f(s2 - mB[j]) * rB[j];
            }
        } else {
            #pragma unroll
            for (int j = 0; j < 4; j++) attn[orowB + (size_t)j * T_ + kt * 16] = 0.f;
        }
        if (kt < kmax) *(short8*)&Ks[(buf ^ 2048) + wofs] = stg;
    }
    // tail zeros beyond kmax
    for (int kt = kmax + 1; kt < 64; ++kt) {
        #pragma unroll
        for (int j = 0; j < 4; j++) {
            attn[orowA + (size_t)j * T_ + kt * 16] = 0.f;
            attn[orowB + (size_t)j * T_ + kt * 16] = 0.f;
        }
    }
}

// ---------------- context ----------------
__global__ __launch_bounds__(128)
void context_kernel(const float* __restrict__ attn, const u16* __restrict__ qkv,
                    float* __restrict__ out) {
    int b = blockIdx.x, h = blockIdx.y, tid = threadIdx.x;
    __shared__ float p[T_];
    const float* prow = attn + (((size_t)(b * H_ + h)) * T_ + (T_ - 1)) * T_;
    for (int i = tid; i < T_; i += 128) p[i] = prow[i];
    __syncthreads();
    size_t vbase = (size_t)b * T_ * NQKV + 2 * D_ + h * HD_ + tid;
    float a0 = 0.f, a1 = 0.f, a2 = 0.f, a3 = 0.f;
    for (int k = 0; k < T_; k += 4) {
        a0 += p[k + 0] * bf2f(qkv[vbase + (size_t)(k + 0) * NQKV]);
        a1 += p[k + 1] * bf2f(qkv[vbase + (size_t)(k + 1) * NQKV]);
        a2 += p[k + 2] * bf2f(qkv[vbase + (size_t)(k + 2) * NQKV]);
        a3 += p[k + 3] * bf2f(qkv[vbase + (size_t)(k + 3) * NQKV]);
    }
    out[(size_t)b * D_ + h * HD_ + tid] = (a0 + a1) + (a2 + a3);
}

extern "C" void kernel_launch(void* const* d_in, const int* in_sizes, int n_in,
                              void* d_out, int out_size, void* d_ws, size_t ws_size,
                              hipStream_t stream) {
    const float* x  = (const float*)d_in[0];
    const float* Wq = (const float*)d_in[1];
    const float* Wk = (const float*)d_in[2];
    const float* Wv = (const float*)d_in[3];
    float* out = (float*)d_out;

    u16* xb  = (u16*)d_ws;
    u16* Wt  = xb + (size_t)B_ * T_ * D_;
    u16* qkv = Wt + (size_t)NQKV * D_;

    int n4 = B_ * T_ * D_ / 4;
    cast_x_kernel<<<n4 / 256, 256, 0, stream>>>(x, xb, n4);
    cast_w_kernel<<<dim3(32, 32, 3), dim3(32, 8), 0, stream>>>(Wq, Wk, Wv, Wt);
    gemm_kernel<<<3072, 256, 0, stream>>>(xb, Wt, qkv);
    attn_kernel<<<1024, 256, 0, stream>>>(qkv, out + B_ * D_);
    context_kernel<<<dim3(B_, H_), 128, 0, stream>>>(out + B_ * D_, qkv, out);
}